// Round 1
// baseline (675.879 us; speedup 1.0000x reference)
//
#include <hip/hip_runtime.h>
#include <math.h>

#define B_ 2
#define S_ 1024
#define H_ 768
#define D_ 24
#define HID_ 96
#define OH_ 768
#define VI_ 2304

static __device__ __forceinline__ float relu_(float x) { return x > 0.f ? x : 0.f; }

#define NEGF (-3.402823466e38f)

// ---------------------------------------------------------------------------
// K1: per-token projections Zj, Zi  [B,S,D]  and per-token precomputes
//     A[t,k] = b_s1[k] + sum_d W_s1[k, d]    * Zj[t,d]
//     Bv[t,k]=           sum_d W_s1[k, 24+d] * Zi[t,d]
// ---------------------------------------------------------------------------
__global__ __launch_bounds__(256) void proj_kernel(
    const float* __restrict__ Hj, const float* __restrict__ Hi,
    const float* __restrict__ Wpj, const float* __restrict__ Wpi,
    const float* __restrict__ Ws1, const float* __restrict__ bs1,
    float* __restrict__ Zj, float* __restrict__ Zi,
    float* __restrict__ Abuf, float* __restrict__ Bbuf)
{
    __shared__ float rowj[H_], rowi[H_], zj[D_], zi[D_];
    const int t = blockIdx.x;           // 0..B*S-1
    const int tid = threadIdx.x;
    const float* hj = Hj + (size_t)t * H_;
    const float* hi = Hi + (size_t)t * H_;
    for (int x = tid; x < H_; x += 256) { rowj[x] = hj[x]; rowi[x] = hi[x]; }
    __syncthreads();

    const int g = tid & 7;              // 8 threads per output
    for (int o = tid >> 3; o < 2 * D_; o += 32) {
        const float* row;
        const float* w;
        if (o < D_) { row = rowj; w = Wpj + o * H_; }
        else        { row = rowi; w = Wpi + (o - D_) * H_; }
        float s = 0.f;
        #pragma unroll 8
        for (int c = 0; c < H_ / 8; ++c) s += row[g + 8 * c] * w[g + 8 * c];
        s += __shfl_down(s, 4, 8);
        s += __shfl_down(s, 2, 8);
        s += __shfl_down(s, 1, 8);
        if (g == 0) {
            if (o < D_) { zj[o] = s;        Zj[(size_t)t * D_ + o] = s; }
            else        { zi[o - D_] = s;   Zi[(size_t)t * D_ + (o - D_)] = s; }
        }
    }
    __syncthreads();

    if (tid < 2 * HID_) {
        const int k = tid % HID_;
        const int half = tid / HID_;    // 0 -> A (uses Zj, cols 0:24), 1 -> Bv (Zi, cols 24:48)
        const float* z = half ? zi : zj;
        const float* w = Ws1 + k * 96 + half * D_;
        float acc = half ? 0.f : bs1[k];
        #pragma unroll
        for (int d = 0; d < D_; ++d) acc += w[d] * z[d];
        if (half) Bbuf[(size_t)t * HID_ + k] = acc;
        else      Abuf[(size_t)t * HID_ + k] = acc;
    }
}

// ---------------------------------------------------------------------------
// K2: pair logits. Block = 16 j x 16 i tile, one thread per pair.
// logit[j,i] = b_s2 + sum_k ws2[k]*relu( A[j,k] + Bv[i,k]
//                  + sum_d W1c[k,d]*(Zj[j,d]*Zi[i,d])
//                  + sum_d W1d[k,d]*|Zj[j,d]-Zi[i,d]| )
// Weight indices are wave-uniform -> compiler scalarizes to s_load.
// ---------------------------------------------------------------------------
__global__ __launch_bounds__(256) void pair_kernel(
    const float* __restrict__ Zj, const float* __restrict__ Zi,
    const float* __restrict__ Abuf, const float* __restrict__ Bbuf,
    const float* __restrict__ Ws1, const float* __restrict__ Ws2,
    const float* __restrict__ bs2,
    float* __restrict__ P)
{
    __shared__ float sZj[16][25], sZi[16][25];   // pad 25: kill stride-24 conflicts
    __shared__ float sA[16][97], sB[16][97];     // pad 97: stride 96 == 0 mod 32!
    __shared__ float sW2[HID_];
    const int j0 = blockIdx.x * 16, i0 = blockIdx.y * 16, b = blockIdx.z;
    const int tid = threadIdx.x;

    for (int x = tid; x < 16 * D_; x += 256) {
        sZj[x / D_][x % D_] = Zj[((size_t)(b * S_ + j0) + x / D_) * D_ + x % D_];
        sZi[x / D_][x % D_] = Zi[((size_t)(b * S_ + i0) + x / D_) * D_ + x % D_];
    }
    for (int x = tid; x < 16 * HID_; x += 256) {
        sA[x / HID_][x % HID_] = Abuf[((size_t)(b * S_ + j0) + x / HID_) * HID_ + x % HID_];
        sB[x / HID_][x % HID_] = Bbuf[((size_t)(b * S_ + i0) + x / HID_) * HID_ + x % HID_];
    }
    if (tid < HID_) sW2[tid] = Ws2[tid];
    __syncthreads();

    const int jj = tid >> 4, ii = tid & 15;
    float f1[D_], f2[D_];
    #pragma unroll
    for (int d = 0; d < D_; ++d) {
        float a = sZj[jj][d], c = sZi[ii][d];
        f1[d] = a * c;
        f2[d] = fabsf(a - c);
    }
    float logit = 0.f;
    for (int k = 0; k < HID_; ++k) {
        const float* wk = Ws1 + k * 96;          // uniform address
        float acc = sA[jj][k] + sB[ii][k];
        float acc2 = 0.f;
        #pragma unroll
        for (int d = 0; d < D_; ++d) {
            acc  += wk[48 + d] * f1[d];
            acc2 += wk[72 + d] * f2[d];
        }
        logit += sW2[k] * relu_(acc + acc2);
    }
    P[((size_t)(b * S_ + j0 + jj)) * S_ + i0 + ii] = logit + bs2[0];
}

// ---------------------------------------------------------------------------
// K3: row softmax over i (with additive key mask), in-place on P
// ---------------------------------------------------------------------------
__global__ __launch_bounds__(256) void softmax_kernel(
    const float* __restrict__ mask, float* __restrict__ P)
{
    const int r = blockIdx.x;           // b*S + j
    const int b = r / S_;
    const int tid = threadIdx.x;
    float* row = P + (size_t)r * S_;
    __shared__ float red[4];

    float v[4];
    float mx = -INFINITY;
    #pragma unroll
    for (int c = 0; c < 4; ++c) {
        int i = tid + 256 * c;
        float m = mask[b * S_ + i];
        v[c] = row[i] + (1.0f - m) * NEGF;
        mx = fmaxf(mx, v[c]);
    }
    for (int off = 32; off > 0; off >>= 1) mx = fmaxf(mx, __shfl_xor(mx, off));
    if ((tid & 63) == 0) red[tid >> 6] = mx;
    __syncthreads();
    mx = fmaxf(fmaxf(red[0], red[1]), fmaxf(red[2], red[3]));

    float s = 0.f;
    #pragma unroll
    for (int c = 0; c < 4; ++c) { v[c] = __expf(v[c] - mx); s += v[c]; }
    for (int off = 32; off > 0; off >>= 1) s += __shfl_xor(s, off);
    __syncthreads();
    if ((tid & 63) == 0) red[tid >> 6] = s;
    __syncthreads();
    s = red[0] + red[1] + red[2] + red[3];
    const float inv = 1.0f / s;
    #pragma unroll
    for (int c = 0; c < 4; ++c) row[tid + 256 * c] = v[c] * inv;
}

// ---------------------------------------------------------------------------
// K4/K5/K6: tiled fp32 GEMM, 64x64 tile, K-chunk 16, 4x4 micro-tile/thread
// MODE 0: ctx = probs @ H_i            (batched, B direct [k,n])
// MODE 1: X1 = relu(msgin @ Wv1^T + b) (A built on the fly, B transposed load)
// MODE 2: out = alpha*(X1 @ Wv2^T + b)
// ---------------------------------------------------------------------------
template<int MODE>
__global__ __launch_bounds__(256) void gemm_kernel(
    const float* __restrict__ Abase, const float* __restrict__ Aux,
    const float* __restrict__ Bbase, const float* __restrict__ bias,
    const float* __restrict__ alphaPtr,
    float* __restrict__ Out, int M, int N, int K)
{
    __shared__ float As[16][68];   // transposed A tile: As[k][m], 272B rows keep 16B align
    __shared__ float Bs[16][64];
    const int m0 = blockIdx.x * 64, n0 = blockIdx.y * 64, bz = blockIdx.z;
    const int tid = threadIdx.x;
    const int tx = tid & 15, ty = tid >> 4;

    const float* Ap = Abase;
    const float* Bp = Bbase;
    if (MODE == 0) { Ap += (size_t)bz * S_ * S_; Bp += (size_t)bz * S_ * H_; }

    float acc[4][4] = {};
    const int arow = tid >> 2, akc = (tid & 3) * 4;

    for (int k0 = 0; k0 < K; k0 += 16) {
        float4 av;
        if (MODE == 1) {
            const int kg = k0 + akc;
            const int seg = kg / 768, kk = kg - seg * 768;
            const float* ctx = Abase + (size_t)(m0 + arow) * 768 + kk;
            const float* hj  = Aux   + (size_t)(m0 + arow) * 768 + kk;
            if (seg == 0)      av = *(const float4*)ctx;
            else if (seg == 1) av = *(const float4*)hj;
            else {
                float4 a = *(const float4*)ctx; float4 h = *(const float4*)hj;
                av = make_float4(a.x * h.x, a.y * h.y, a.z * h.z, a.w * h.w);
            }
        } else {
            av = *(const float4*)(Ap + (size_t)(m0 + arow) * K + k0 + akc);
        }
        As[akc + 0][arow] = av.x; As[akc + 1][arow] = av.y;
        As[akc + 2][arow] = av.z; As[akc + 3][arow] = av.w;

        if (MODE == 0) {
            const int kr = tid >> 4, nc = (tid & 15) * 4;
            float4 bv = *(const float4*)(Bp + (size_t)(k0 + kr) * N + n0 + nc);
            *(float4*)&Bs[kr][nc] = bv;
        } else {
            const int n = tid >> 2, kc = (tid & 3) * 4;
            float4 bv = *(const float4*)(Bp + (size_t)(n0 + n) * K + k0 + kc);
            Bs[kc + 0][n] = bv.x; Bs[kc + 1][n] = bv.y;
            Bs[kc + 2][n] = bv.z; Bs[kc + 3][n] = bv.w;
        }
        __syncthreads();

        #pragma unroll
        for (int kk = 0; kk < 16; ++kk) {
            float4 a  = *(const float4*)&As[kk][ty * 4];
            float4 bv = *(const float4*)&Bs[kk][tx * 4];
            float ar[4] = {a.x, a.y, a.z, a.w};
            float br[4] = {bv.x, bv.y, bv.z, bv.w};
            #pragma unroll
            for (int r = 0; r < 4; ++r)
                #pragma unroll
                for (int c = 0; c < 4; ++c)
                    acc[r][c] += ar[r] * br[c];
        }
        __syncthreads();
    }

    const float alpha = (MODE == 2) ? alphaPtr[0] : 0.f;
    #pragma unroll
    for (int r = 0; r < 4; ++r) {
        const int m = m0 + ty * 4 + r;
        #pragma unroll
        for (int c = 0; c < 4; ++c) {
            const int n = n0 + tx * 4 + c;
            float v = acc[r][c];
            if (MODE == 0) {
                Out[((size_t)bz * S_ + m) * H_ + n] = v;
            } else if (MODE == 1) {
                v += bias[n];
                Out[(size_t)m * N + n] = relu_(v);
            } else {
                Out[(size_t)m * N + n] = alpha * (v + bias[n]);
            }
        }
    }
}

// ---------------------------------------------------------------------------
extern "C" void kernel_launch(void* const* d_in, const int* in_sizes, int n_in,
                              void* d_out, int out_size, void* d_ws, size_t ws_size,
                              hipStream_t stream)
{
    (void)in_sizes; (void)n_in; (void)out_size; (void)ws_size;
    const float* Hj   = (const float*)d_in[0];
    const float* Hi   = (const float*)d_in[1];
    const float* mask = (const float*)d_in[2];
    const float* Wpj  = (const float*)d_in[3];
    const float* Wpi  = (const float*)d_in[4];
    const float* Ws1  = (const float*)d_in[5];
    const float* bs1  = (const float*)d_in[6];
    const float* Ws2  = (const float*)d_in[7];
    const float* bs2  = (const float*)d_in[8];
    const float* Wv1  = (const float*)d_in[9];
    const float* bv1  = (const float*)d_in[10];
    const float* Wv2  = (const float*)d_in[11];
    const float* bv2  = (const float*)d_in[12];
    const float* alphaPtr = (const float*)d_in[13];
    float* out = (float*)d_out;

    float* ws  = (float*)d_ws;
    float* Zj   = ws;                          // B*S*D
    float* Zi   = Zj + (size_t)B_ * S_ * D_;
    float* Abuf = Zi + (size_t)B_ * S_ * D_;   // B*S*HID
    float* Bbuf = Abuf + (size_t)B_ * S_ * HID_;
    float* P    = Bbuf + (size_t)B_ * S_ * HID_;  // B*S*S (logits -> probs)
    float* CTX  = P + (size_t)B_ * S_ * S_;    // B*S*H
    float* X1   = P;                           // reuse P region after ctx GEMM (needs B*S*OH <= B*S*S)

    proj_kernel<<<B_ * S_, 256, 0, stream>>>(Hj, Hi, Wpj, Wpi, Ws1, bs1, Zj, Zi, Abuf, Bbuf);
    pair_kernel<<<dim3(S_ / 16, S_ / 16, B_), 256, 0, stream>>>(Zj, Zi, Abuf, Bbuf, Ws1, Ws2, bs2, P);
    softmax_kernel<<<B_ * S_, 256, 0, stream>>>(mask, P);
    gemm_kernel<0><<<dim3(S_ / 64, H_ / 64, B_), 256, 0, stream>>>(
        P, nullptr, Hi, nullptr, nullptr, CTX, S_, H_, S_);
    gemm_kernel<1><<<dim3(B_ * S_ / 64, OH_ / 64, 1), 256, 0, stream>>>(
        CTX, Hj, Wv1, bv1, nullptr, X1, B_ * S_, OH_, VI_);
    gemm_kernel<2><<<dim3(B_ * S_ / 64, H_ / 64, 1), 256, 0, stream>>>(
        X1, nullptr, Wv2, bv2, alphaPtr, out, B_ * S_, H_, OH_);
}

// Round 2
// 474.592 us; speedup vs baseline: 1.4241x; 1.4241x over previous
//
#include <hip/hip_runtime.h>
#include <hip/hip_bf16.h>
#include <math.h>

#define B_ 2
#define S_ 1024
#define H_ 768
#define D_ 24
#define HID_ 96
#define OH_ 768
#define VI_ 2304

typedef short bf16x8 __attribute__((ext_vector_type(8)));
typedef float f32x4 __attribute__((ext_vector_type(4)));

static __device__ __forceinline__ float relu_(float x) { return x > 0.f ? x : 0.f; }

static __device__ __forceinline__ short f2bf(float f) {
    __hip_bfloat16 h = __float2bfloat16(f);
    return *reinterpret_cast<short*>(&h);
}

#define NEGF (-3.402823466e38f)

// ---------------------------------------------------------------------------
// K1: per-token projections Zj, Zi  [B,S,D]
// ---------------------------------------------------------------------------
__global__ __launch_bounds__(256) void proj_kernel(
    const float* __restrict__ Hj, const float* __restrict__ Hi,
    const float* __restrict__ Wpj, const float* __restrict__ Wpi,
    float* __restrict__ Zj, float* __restrict__ Zi)
{
    __shared__ float rowj[H_], rowi[H_];
    const int t = blockIdx.x;           // 0..B*S-1
    const int tid = threadIdx.x;
    const float* hj = Hj + (size_t)t * H_;
    const float* hi = Hi + (size_t)t * H_;
    for (int x = tid; x < H_; x += 256) { rowj[x] = hj[x]; rowi[x] = hi[x]; }
    __syncthreads();

    const int g = tid & 7;              // 8 threads per output
    for (int o = tid >> 3; o < 2 * D_; o += 32) {
        const float* row;
        const float* w;
        if (o < D_) { row = rowj; w = Wpj + o * H_; }
        else        { row = rowi; w = Wpi + (o - D_) * H_; }
        float s = 0.f;
        #pragma unroll 8
        for (int c = 0; c < H_ / 8; ++c) s += row[g + 8 * c] * w[g + 8 * c];
        s += __shfl_down(s, 4, 8);
        s += __shfl_down(s, 2, 8);
        s += __shfl_down(s, 1, 8);
        if (g == 0) {
            if (o < D_) Zj[(size_t)t * D_ + o] = s;
            else        Zi[(size_t)t * D_ + (o - D_)] = s;
        }
    }
}

// ---------------------------------------------------------------------------
// K2: pair logits via MFMA. Block = 16 j x 64 i pairs, 4 waves.
// Features per pair (K=96): [Zj(24), Zi(24), Zj*Zi(24), |Zj-Zi|(24)]
// h = F @ W_s1^T  via 16x16x32 bf16 MFMA, 3 K-steps, 6 N-tiles (96 outputs)
// logit = sum_k w2[k]*relu(h[k]+b1[k]) + b2
// Frag layout (m89-verified): A row=lane&15 (pair), k=8*(lane>>4)+e;
// B col=lane&15 (output k), same k; D col=lane&15, row=4*(lane>>4)+reg.
// ---------------------------------------------------------------------------
__global__ __launch_bounds__(256) void pair_mfma_kernel(
    const float* __restrict__ Zj, const float* __restrict__ Zi,
    const float* __restrict__ Ws1, const float* __restrict__ Ws2,
    const float* __restrict__ bs1, const float* __restrict__ bs2,
    float* __restrict__ P)
{
    __shared__ float sZj32[16][28];   // stride 28 floats: 16B-aligned rows
    __shared__ float sZi32[64][28];
    __shared__ short sZj16[16][24];   // 48B rows, 16B aligned
    __shared__ short sZi16[64][24];

    const int j0 = blockIdx.x * 16, i0 = blockIdx.y * 64, b = blockIdx.z;
    const int tid = threadIdx.x;
    const int lane = tid & 63, wv = tid >> 6;
    const int q = lane & 15, g = lane >> 4;

    // stage Zj/Zi tiles (fp32 + bf16 copies)
    for (int x = tid; x < 16 * D_; x += 256) {
        int r = x / D_, c = x % D_;
        float v = Zj[((size_t)(b * S_ + j0 + r)) * D_ + c];
        sZj32[r][c] = v; sZj16[r][c] = f2bf(v);
    }
    for (int x = tid; x < 64 * D_; x += 256) {
        int r = x / D_, c = x % D_;
        float v = Zi[((size_t)(b * S_ + i0 + r)) * D_ + c];
        sZi32[r][c] = v; sZi16[r][c] = f2bf(v);
    }

    // weight fragments: wf[nt][ks], lane holds W_s1[nt*16+q][ks*32+g*8 .. +7]
    bf16x8 wf[6][3];
    #pragma unroll
    for (int nt = 0; nt < 6; ++nt)
        #pragma unroll
        for (int ks = 0; ks < 3; ++ks) {
            const float* wp = Ws1 + (size_t)(nt * 16 + q) * 96 + ks * 32 + g * 8;
            bf16x8 t8;
            #pragma unroll
            for (int e = 0; e < 8; ++e) t8[e] = f2bf(wp[e]);
            wf[nt][ks] = t8;
        }
    float bias_r[6], w2_r[6];
    #pragma unroll
    for (int nt = 0; nt < 6; ++nt) {
        bias_r[nt] = bs1[nt * 16 + q];
        w2_r[nt]   = Ws2[nt * 16 + q];
    }
    const float b2 = bs2[0];
    __syncthreads();

    // each wave: 16 M-tiles of 16 pairs (jj = t>>2, ii = (t&3)*16 + q)
    for (int m = 0; m < 16; ++m) {
        const int t = wv * 16 + m;
        const int jj = t >> 2, iibase = (t & 3) * 16;
        const int ii = iibase + q;

        bf16x8 af[3];
        #pragma unroll
        for (int ks = 0; ks < 3; ++ks) {
            const int c = ks * 4 + g;       // chunk 0..11
            bf16x8 t8;
            if (c < 3) {                    // Zj chunk (uniform in group)
                t8 = *(const bf16x8*)&sZj16[jj][c * 8];
            } else if (c < 6) {             // Zi chunk
                t8 = *(const bf16x8*)&sZi16[ii][(c - 3) * 8];
            } else if (c < 9) {             // hadamard chunk
                const float* zja = &sZj32[jj][(c - 6) * 8];
                const float* zia = &sZi32[ii][(c - 6) * 8];
                #pragma unroll
                for (int e = 0; e < 8; ++e) t8[e] = f2bf(zja[e] * zia[e]);
            } else {                        // abs-diff chunk
                const float* zja = &sZj32[jj][(c - 9) * 8];
                const float* zia = &sZi32[ii][(c - 9) * 8];
                #pragma unroll
                for (int e = 0; e < 8; ++e) t8[e] = f2bf(fabsf(zja[e] - zia[e]));
            }
            af[ks] = t8;
        }

        f32x4 acc[6];
        #pragma unroll
        for (int nt = 0; nt < 6; ++nt) {
            f32x4 a = {0.f, 0.f, 0.f, 0.f};
            a = __builtin_amdgcn_mfma_f32_16x16x32_bf16(af[0], wf[nt][0], a, 0, 0, 0);
            a = __builtin_amdgcn_mfma_f32_16x16x32_bf16(af[1], wf[nt][1], a, 0, 0, 0);
            a = __builtin_amdgcn_mfma_f32_16x16x32_bf16(af[2], wf[nt][2], a, 0, 0, 0);
            acc[nt] = a;
        }

        // epilogue: relu + dot with w2, reduce over k (cols q, tiles nt)
        float lg[4] = {0.f, 0.f, 0.f, 0.f};
        #pragma unroll
        for (int nt = 0; nt < 6; ++nt)
            #pragma unroll
            for (int r = 0; r < 4; ++r)
                lg[r] += w2_r[nt] * relu_(acc[nt][r] + bias_r[nt]);
        #pragma unroll
        for (int msk = 8; msk >= 1; msk >>= 1)
            #pragma unroll
            for (int r = 0; r < 4; ++r) lg[r] += __shfl_xor(lg[r], msk);

        if (q == 0) {
            float4 o = make_float4(lg[0] + b2, lg[1] + b2, lg[2] + b2, lg[3] + b2);
            *(float4*)&P[((size_t)(b * S_ + j0 + jj)) * S_ + i0 + iibase + g * 4] = o;
        }
    }
}

// ---------------------------------------------------------------------------
// K3: row softmax over i (with additive key mask), in-place on P
// ---------------------------------------------------------------------------
__global__ __launch_bounds__(256) void softmax_kernel(
    const float* __restrict__ mask, float* __restrict__ P)
{
    const int r = blockIdx.x;           // b*S + j
    const int b = r / S_;
    const int tid = threadIdx.x;
    float* row = P + (size_t)r * S_;
    __shared__ float red[4];

    float v[4];
    float mx = -INFINITY;
    #pragma unroll
    for (int c = 0; c < 4; ++c) {
        int i = tid + 256 * c;
        float m = mask[b * S_ + i];
        v[c] = row[i] + (1.0f - m) * NEGF;
        mx = fmaxf(mx, v[c]);
    }
    for (int off = 32; off > 0; off >>= 1) mx = fmaxf(mx, __shfl_xor(mx, off));
    if ((tid & 63) == 0) red[tid >> 6] = mx;
    __syncthreads();
    mx = fmaxf(fmaxf(red[0], red[1]), fmaxf(red[2], red[3]));

    float s = 0.f;
    #pragma unroll
    for (int c = 0; c < 4; ++c) { v[c] = __expf(v[c] - mx); s += v[c]; }
    for (int off = 32; off > 0; off >>= 1) s += __shfl_xor(s, off);
    __syncthreads();
    if ((tid & 63) == 0) red[tid >> 6] = s;
    __syncthreads();
    s = red[0] + red[1] + red[2] + red[3];
    const float inv = 1.0f / s;
    #pragma unroll
    for (int c = 0; c < 4; ++c) row[tid + 256 * c] = v[c] * inv;
}

// ---------------------------------------------------------------------------
// K4/K5/K6: tiled fp32 GEMM, 64x64 tile, K-chunk 16, 4x4 micro-tile/thread
// MODE 0: ctx = probs @ H_i            (batched, B direct [k,n])
// MODE 1: X1 = relu(msgin @ Wv1^T + b) (A built on the fly, B transposed load)
// MODE 2: out = alpha*(X1 @ Wv2^T + b)
// ---------------------------------------------------------------------------
template<int MODE>
__global__ __launch_bounds__(256) void gemm_kernel(
    const float* __restrict__ Abase, const float* __restrict__ Aux,
    const float* __restrict__ Bbase, const float* __restrict__ bias,
    const float* __restrict__ alphaPtr,
    float* __restrict__ Out, int M, int N, int K)
{
    __shared__ float As[16][68];   // transposed A tile: As[k][m]
    __shared__ float Bs[16][64];
    const int m0 = blockIdx.x * 64, n0 = blockIdx.y * 64, bz = blockIdx.z;
    const int tid = threadIdx.x;
    const int tx = tid & 15, ty = tid >> 4;

    const float* Ap = Abase;
    const float* Bp = Bbase;
    if (MODE == 0) { Ap += (size_t)bz * S_ * S_; Bp += (size_t)bz * S_ * H_; }

    float acc[4][4] = {};
    const int arow = tid >> 2, akc = (tid & 3) * 4;

    for (int k0 = 0; k0 < K; k0 += 16) {
        float4 av;
        if (MODE == 1) {
            const int kg = k0 + akc;
            const int seg = kg / 768, kk = kg - seg * 768;
            const float* ctx = Abase + (size_t)(m0 + arow) * 768 + kk;
            const float* hj  = Aux   + (size_t)(m0 + arow) * 768 + kk;
            if (seg == 0)      av = *(const float4*)ctx;
            else if (seg == 1) av = *(const float4*)hj;
            else {
                float4 a = *(const float4*)ctx; float4 h = *(const float4*)hj;
                av = make_float4(a.x * h.x, a.y * h.y, a.z * h.z, a.w * h.w);
            }
        } else {
            av = *(const float4*)(Ap + (size_t)(m0 + arow) * K + k0 + akc);
        }
        As[akc + 0][arow] = av.x; As[akc + 1][arow] = av.y;
        As[akc + 2][arow] = av.z; As[akc + 3][arow] = av.w;

        if (MODE == 0) {
            const int kr = tid >> 4, nc = (tid & 15) * 4;
            float4 bv = *(const float4*)(Bp + (size_t)(k0 + kr) * N + n0 + nc);
            *(float4*)&Bs[kr][nc] = bv;
        } else {
            const int n = tid >> 2, kc = (tid & 3) * 4;
            float4 bv = *(const float4*)(Bp + (size_t)(n0 + n) * K + k0 + kc);
            Bs[kc + 0][n] = bv.x; Bs[kc + 1][n] = bv.y;
            Bs[kc + 2][n] = bv.z; Bs[kc + 3][n] = bv.w;
        }
        __syncthreads();

        #pragma unroll
        for (int kk = 0; kk < 16; ++kk) {
            float4 a  = *(const float4*)&As[kk][ty * 4];
            float4 bv = *(const float4*)&Bs[kk][tx * 4];
            float ar[4] = {a.x, a.y, a.z, a.w};
            float br[4] = {bv.x, bv.y, bv.z, bv.w};
            #pragma unroll
            for (int r = 0; r < 4; ++r)
                #pragma unroll
                for (int c = 0; c < 4; ++c)
                    acc[r][c] += ar[r] * br[c];
        }
        __syncthreads();
    }

    const float alpha = (MODE == 2) ? alphaPtr[0] : 0.f;
    #pragma unroll
    for (int r = 0; r < 4; ++r) {
        const int m = m0 + ty * 4 + r;
        #pragma unroll
        for (int c = 0; c < 4; ++c) {
            const int n = n0 + tx * 4 + c;
            float v = acc[r][c];
            if (MODE == 0) {
                Out[((size_t)bz * S_ + m) * H_ + n] = v;
            } else if (MODE == 1) {
                v += bias[n];
                Out[(size_t)m * N + n] = relu_(v);
            } else {
                Out[(size_t)m * N + n] = alpha * (v + bias[n]);
            }
        }
    }
}

// ---------------------------------------------------------------------------
extern "C" void kernel_launch(void* const* d_in, const int* in_sizes, int n_in,
                              void* d_out, int out_size, void* d_ws, size_t ws_size,
                              hipStream_t stream)
{
    (void)in_sizes; (void)n_in; (void)out_size; (void)ws_size;
    const float* Hj   = (const float*)d_in[0];
    const float* Hi   = (const float*)d_in[1];
    const float* mask = (const float*)d_in[2];
    const float* Wpj  = (const float*)d_in[3];
    const float* Wpi  = (const float*)d_in[4];
    const float* Ws1  = (const float*)d_in[5];
    const float* bs1  = (const float*)d_in[6];
    const float* Ws2  = (const float*)d_in[7];
    const float* bs2  = (const float*)d_in[8];
    const float* Wv1  = (const float*)d_in[9];
    const float* bv1  = (const float*)d_in[10];
    const float* Wv2  = (const float*)d_in[11];
    const float* bv2  = (const float*)d_in[12];
    const float* alphaPtr = (const float*)d_in[13];
    float* out = (float*)d_out;

    float* ws  = (float*)d_ws;
    float* Zj   = ws;                          // B*S*D
    float* Zi   = Zj + (size_t)B_ * S_ * D_;
    float* P    = Zi + (size_t)B_ * S_ * D_;   // B*S*S (logits -> probs)
    float* CTX  = P + (size_t)B_ * S_ * S_;    // B*S*H
    float* X1   = P;                           // reuse P after ctx GEMM

    proj_kernel<<<B_ * S_, 256, 0, stream>>>(Hj, Hi, Wpj, Wpi, Zj, Zi);
    pair_mfma_kernel<<<dim3(S_ / 16, S_ / 64, B_), 256, 0, stream>>>(
        Zj, Zi, Ws1, Ws2, bs1, bs2, P);
    softmax_kernel<<<B_ * S_, 256, 0, stream>>>(mask, P);
    gemm_kernel<0><<<dim3(S_ / 64, H_ / 64, B_), 256, 0, stream>>>(
        P, nullptr, Hi, nullptr, nullptr, CTX, S_, H_, S_);
    gemm_kernel<1><<<dim3(B_ * S_ / 64, OH_ / 64, 1), 256, 0, stream>>>(
        CTX, Hj, Wv1, bv1, nullptr, X1, B_ * S_, OH_, VI_);
    gemm_kernel<2><<<dim3(B_ * S_ / 64, H_ / 64, 1), 256, 0, stream>>>(
        X1, nullptr, Wv2, bv2, alphaPtr, out, B_ * S_, H_, OH_);
}

// Round 3
// 265.494 us; speedup vs baseline: 2.5457x; 1.7876x over previous
//
#include <hip/hip_runtime.h>
#include <hip/hip_bf16.h>
#include <math.h>

#define B_ 2
#define S_ 1024
#define H_ 768
#define D_ 24
#define HID_ 96
#define OH_ 768
#define VI_ 2304

typedef short bf16x8 __attribute__((ext_vector_type(8)));
typedef float f32x4 __attribute__((ext_vector_type(4)));
typedef unsigned short u16;

static __device__ __forceinline__ float relu_(float x) { return x > 0.f ? x : 0.f; }

static __device__ __forceinline__ short f2bf(float f) {
    __hip_bfloat16 h = __float2bfloat16(f);
    return *reinterpret_cast<short*>(&h);
}
static __device__ __forceinline__ float bf2f(short s) {
    unsigned u = ((unsigned)(u16)s) << 16;
    return __uint_as_float(u);
}

static __device__ __forceinline__ void gl_lds16(const void* g, void* l) {
    __builtin_amdgcn_global_load_lds(
        (const __attribute__((address_space(1))) unsigned int*)g,
        (__attribute__((address_space(3))) unsigned int*)l, 16, 0, 0);
}

#define NEGF (-3.402823466e38f)

// ---------------------------------------------------------------------------
// K1: per-token projections Zj, Zi  [B,S,D]
// ---------------------------------------------------------------------------
__global__ __launch_bounds__(256) void proj_kernel(
    const float* __restrict__ Hj, const float* __restrict__ Hi,
    const float* __restrict__ Wpj, const float* __restrict__ Wpi,
    float* __restrict__ Zj, float* __restrict__ Zi)
{
    __shared__ float rowj[H_], rowi[H_];
    const int t = blockIdx.x;           // 0..B*S-1
    const int tid = threadIdx.x;
    const float* hj = Hj + (size_t)t * H_;
    const float* hi = Hi + (size_t)t * H_;
    for (int x = tid; x < H_; x += 256) { rowj[x] = hj[x]; rowi[x] = hi[x]; }
    __syncthreads();

    const int g = tid & 7;              // 8 threads per output
    for (int o = tid >> 3; o < 2 * D_; o += 32) {
        const float* row;
        const float* w;
        if (o < D_) { row = rowj; w = Wpj + o * H_; }
        else        { row = rowi; w = Wpi + (o - D_) * H_; }
        float s = 0.f;
        #pragma unroll 8
        for (int c = 0; c < H_ / 8; ++c) s += row[g + 8 * c] * w[g + 8 * c];
        s += __shfl_down(s, 4, 8);
        s += __shfl_down(s, 2, 8);
        s += __shfl_down(s, 1, 8);
        if (g == 0) {
            if (o < D_) Zj[(size_t)t * D_ + o] = s;
            else        Zi[(size_t)t * D_ + (o - D_)] = s;
        }
    }
}

// ---------------------------------------------------------------------------
// K2: pair logits via MFMA (unchanged from round 2)
// ---------------------------------------------------------------------------
__global__ __launch_bounds__(256) void pair_mfma_kernel(
    const float* __restrict__ Zj, const float* __restrict__ Zi,
    const float* __restrict__ Ws1, const float* __restrict__ Ws2,
    const float* __restrict__ bs1, const float* __restrict__ bs2,
    float* __restrict__ P)
{
    __shared__ float sZj32[16][28];
    __shared__ float sZi32[64][28];
    __shared__ short sZj16[16][24];
    __shared__ short sZi16[64][24];

    const int j0 = blockIdx.x * 16, i0 = blockIdx.y * 64, b = blockIdx.z;
    const int tid = threadIdx.x;
    const int lane = tid & 63, wv = tid >> 6;
    const int q = lane & 15, g = lane >> 4;

    for (int x = tid; x < 16 * D_; x += 256) {
        int r = x / D_, c = x % D_;
        float v = Zj[((size_t)(b * S_ + j0 + r)) * D_ + c];
        sZj32[r][c] = v; sZj16[r][c] = f2bf(v);
    }
    for (int x = tid; x < 64 * D_; x += 256) {
        int r = x / D_, c = x % D_;
        float v = Zi[((size_t)(b * S_ + i0 + r)) * D_ + c];
        sZi32[r][c] = v; sZi16[r][c] = f2bf(v);
    }

    bf16x8 wf[6][3];
    #pragma unroll
    for (int nt = 0; nt < 6; ++nt)
        #pragma unroll
        for (int ks = 0; ks < 3; ++ks) {
            const float* wp = Ws1 + (size_t)(nt * 16 + q) * 96 + ks * 32 + g * 8;
            bf16x8 t8;
            #pragma unroll
            for (int e = 0; e < 8; ++e) t8[e] = f2bf(wp[e]);
            wf[nt][ks] = t8;
        }
    float bias_r[6], w2_r[6];
    #pragma unroll
    for (int nt = 0; nt < 6; ++nt) {
        bias_r[nt] = bs1[nt * 16 + q];
        w2_r[nt]   = Ws2[nt * 16 + q];
    }
    const float b2 = bs2[0];
    __syncthreads();

    for (int m = 0; m < 16; ++m) {
        const int t = wv * 16 + m;
        const int jj = t >> 2, iibase = (t & 3) * 16;
        const int ii = iibase + q;

        bf16x8 af[3];
        #pragma unroll
        for (int ks = 0; ks < 3; ++ks) {
            const int c = ks * 4 + g;
            bf16x8 t8;
            if (c < 3) {
                t8 = *(const bf16x8*)&sZj16[jj][c * 8];
            } else if (c < 6) {
                t8 = *(const bf16x8*)&sZi16[ii][(c - 3) * 8];
            } else if (c < 9) {
                const float* zja = &sZj32[jj][(c - 6) * 8];
                const float* zia = &sZi32[ii][(c - 6) * 8];
                #pragma unroll
                for (int e = 0; e < 8; ++e) t8[e] = f2bf(zja[e] * zia[e]);
            } else {
                const float* zja = &sZj32[jj][(c - 9) * 8];
                const float* zia = &sZi32[ii][(c - 9) * 8];
                #pragma unroll
                for (int e = 0; e < 8; ++e) t8[e] = f2bf(fabsf(zja[e] - zia[e]));
            }
            af[ks] = t8;
        }

        f32x4 acc[6];
        #pragma unroll
        for (int nt = 0; nt < 6; ++nt) {
            f32x4 a = {0.f, 0.f, 0.f, 0.f};
            a = __builtin_amdgcn_mfma_f32_16x16x32_bf16(af[0], wf[nt][0], a, 0, 0, 0);
            a = __builtin_amdgcn_mfma_f32_16x16x32_bf16(af[1], wf[nt][1], a, 0, 0, 0);
            a = __builtin_amdgcn_mfma_f32_16x16x32_bf16(af[2], wf[nt][2], a, 0, 0, 0);
            acc[nt] = a;
        }

        float lg[4] = {0.f, 0.f, 0.f, 0.f};
        #pragma unroll
        for (int nt = 0; nt < 6; ++nt)
            #pragma unroll
            for (int r = 0; r < 4; ++r)
                lg[r] += w2_r[nt] * relu_(acc[nt][r] + bias_r[nt]);
        #pragma unroll
        for (int msk = 8; msk >= 1; msk >>= 1)
            #pragma unroll
            for (int r = 0; r < 4; ++r) lg[r] += __shfl_xor(lg[r], msk);

        if (q == 0) {
            float4 o = make_float4(lg[0] + b2, lg[1] + b2, lg[2] + b2, lg[3] + b2);
            *(float4*)&P[((size_t)(b * S_ + j0 + jj)) * S_ + i0 + iibase + g * 4] = o;
        }
    }
}

// ---------------------------------------------------------------------------
// K3: row softmax over i (additive key mask); reads fp32 logits, writes bf16
// ---------------------------------------------------------------------------
__global__ __launch_bounds__(256) void softmax_kernel(
    const float* __restrict__ mask, const float* __restrict__ P,
    u16* __restrict__ Pb)
{
    const int r = blockIdx.x;           // b*S + j
    const int b = r / S_;
    const int tid = threadIdx.x;
    const float* row = P + (size_t)r * S_;
    __shared__ float red[4];

    float v[4];
    float mx = -INFINITY;
    #pragma unroll
    for (int c = 0; c < 4; ++c) {
        int i = tid + 256 * c;
        float m = mask[b * S_ + i];
        v[c] = row[i] + (1.0f - m) * NEGF;
        mx = fmaxf(mx, v[c]);
    }
    for (int off = 32; off > 0; off >>= 1) mx = fmaxf(mx, __shfl_xor(mx, off));
    if ((tid & 63) == 0) red[tid >> 6] = mx;
    __syncthreads();
    mx = fmaxf(fmaxf(red[0], red[1]), fmaxf(red[2], red[3]));

    float s = 0.f;
    #pragma unroll
    for (int c = 0; c < 4; ++c) { v[c] = __expf(v[c] - mx); s += v[c]; }
    for (int off = 32; off > 0; off >>= 1) s += __shfl_xor(s, off);
    __syncthreads();
    if ((tid & 63) == 0) red[tid >> 6] = s;
    __syncthreads();
    s = red[0] + red[1] + red[2] + red[3];
    const float inv = 1.0f / s;
    #pragma unroll
    for (int c = 0; c < 4; ++c)
        Pb[(size_t)r * S_ + tid + 256 * c] = (u16)f2bf(v[c] * inv);
}

// ---------------------------------------------------------------------------
// Prep kernels: fp32->bf16 convert, Hi transpose, msg_in build
// ---------------------------------------------------------------------------
__global__ __launch_bounds__(256) void cvt_kernel(
    const float* __restrict__ src, u16* __restrict__ dst, int n4)
{
    int i = blockIdx.x * 256 + threadIdx.x;
    if (i >= n4) return;
    float4 v = ((const float4*)src)[i];
    ushort4 o;
    o.x = (u16)f2bf(v.x); o.y = (u16)f2bf(v.y);
    o.z = (u16)f2bf(v.z); o.w = (u16)f2bf(v.w);
    ((ushort4*)dst)[i] = o;
}

__global__ __launch_bounds__(256) void transpose_hi_kernel(
    const float* __restrict__ Hi, u16* __restrict__ HiT)
{
    __shared__ u16 t[32][33];
    const int i0 = blockIdx.x * 32, h0 = blockIdx.y * 32, b = blockIdx.z;
    const int c = threadIdx.x & 31, r = threadIdx.x >> 5;   // r: 0..7
    #pragma unroll
    for (int rr = r; rr < 32; rr += 8)
        t[rr][c] = (u16)f2bf(Hi[((size_t)(b * S_ + i0 + rr)) * H_ + h0 + c]);
    __syncthreads();
    #pragma unroll
    for (int rr = r; rr < 32; rr += 8)
        HiT[((size_t)(b * H_ + h0 + rr)) * S_ + i0 + c] = t[c][rr];
}

__global__ __launch_bounds__(256) void msgin_kernel(
    const u16* __restrict__ ctx, const float* __restrict__ Hj,
    u16* __restrict__ MSG)
{
    const int idx = blockIdx.x * 256 + threadIdx.x;   // < 2048*96
    const int m = idx / 96, c8 = (idx % 96) * 8;
    bf16x8 c = *(const bf16x8*)&ctx[(size_t)m * H_ + c8];
    float4 h0 = *(const float4*)&Hj[(size_t)m * H_ + c8];
    float4 h1 = *(const float4*)&Hj[(size_t)m * H_ + c8 + 4];
    float hf[8] = {h0.x, h0.y, h0.z, h0.w, h1.x, h1.y, h1.z, h1.w};
    bf16x8 hb, pb;
    #pragma unroll
    for (int e = 0; e < 8; ++e) {
        hb[e] = f2bf(hf[e]);
        pb[e] = f2bf(bf2f(c[e]) * hf[e]);
    }
    u16* row = MSG + (size_t)m * VI_;
    *(bf16x8*)&row[c8]        = c;
    *(bf16x8*)&row[768 + c8]  = hb;
    *(bf16x8*)&row[1536 + c8] = pb;
}

// ---------------------------------------------------------------------------
// bf16 MFMA GEMM: C[2048,768] = A[2048,K] x B[768,K]^T
// 64x64 tile, BK=64, 4 waves (2x2, 32x32 each), dbuf LDS, global_load_lds(16),
// chunk-XOR swizzle (c ^= row&7) pre-applied on global source, applied on read.
// MODE 0: A=Pb(batched rows), B=HiT(+batch), out bf16 CTX
// MODE 1: A=MSG, B=Wv1b, bias+relu, out bf16 X1
// MODE 2: A=X1, B=Wv2b, alpha*(v+bias), out fp32
// ---------------------------------------------------------------------------
template<int MODE, int K>
__global__ __launch_bounds__(256) void mfma_gemm_kernel(
    const u16* __restrict__ Ag, const u16* __restrict__ Bg,
    const float* __restrict__ bias, const float* __restrict__ alphaPtr,
    void* __restrict__ Outv)
{
    __shared__ u16 As[2][64 * 64];
    __shared__ u16 Bs[2][64 * 64];
    const int tid = threadIdx.x;
    const int lane = tid & 63, wv = tid >> 6;
    const int q = lane & 15, g = lane >> 4;
    const int wr = wv >> 1, wc = wv & 1;
    const int m0 = blockIdx.x * 64, n0 = blockIdx.y * 64;

    const u16* Ab = Ag + (size_t)m0 * K;
    const u16* Bb = (MODE == 0)
        ? Bg + (size_t)(m0 >> 10) * H_ * S_ + (size_t)n0 * K
        : Bg + (size_t)n0 * K;

    // staging lane constants: cidx = (it*4+wv)*64 + lane
    int st_r[2], st_gc[2], st_dst[2];
    #pragma unroll
    for (int it = 0; it < 2; ++it) {
        int cidx = (it * 4 + wv) * 64 + lane;
        st_r[it] = cidx >> 3;
        st_gc[it] = (cidx & 7) ^ (st_r[it] & 7);
        st_dst[it] = cidx * 8;              // u16 offset
    }

    f32x4 acc[2][2] = {};

    auto stage = [&](int buf, int k0) {
        #pragma unroll
        for (int it = 0; it < 2; ++it) {
            gl_lds16(Ab + (size_t)st_r[it] * K + k0 + st_gc[it] * 8,
                     &As[buf][st_dst[it]]);
            gl_lds16(Bb + (size_t)st_r[it] * K + k0 + st_gc[it] * 8,
                     &Bs[buf][st_dst[it]]);
        }
    };
    auto comp = [&](int buf) {
        #pragma unroll
        for (int ks = 0; ks < 2; ++ks) {
            bf16x8 af[2], bfr[2];
            #pragma unroll
            for (int m = 0; m < 2; ++m) {
                int r = wr * 32 + m * 16 + q;
                int cl = (g + ks * 4) ^ (r & 7);
                af[m] = *(const bf16x8*)&As[buf][r * 64 + cl * 8];
            }
            #pragma unroll
            for (int n = 0; n < 2; ++n) {
                int r = wc * 32 + n * 16 + q;
                int cl = (g + ks * 4) ^ (r & 7);
                bfr[n] = *(const bf16x8*)&Bs[buf][r * 64 + cl * 8];
            }
            #pragma unroll
            for (int m = 0; m < 2; ++m)
                #pragma unroll
                for (int n = 0; n < 2; ++n)
                    acc[m][n] = __builtin_amdgcn_mfma_f32_16x16x32_bf16(
                        af[m], bfr[n], acc[m][n], 0, 0, 0);
        }
    };

    constexpr int NT = K / 64;
    stage(0, 0);
    __syncthreads();
    int cur = 0;
    for (int kt = 0; kt < NT - 1; ++kt) {
        stage(cur ^ 1, (kt + 1) * 64);
        comp(cur);
        __syncthreads();
        cur ^= 1;
    }
    comp(cur);

    // epilogue
    const float alpha = (MODE == 2) ? alphaPtr[0] : 0.f;
    u16* O16 = (u16*)Outv;
    float* Of = (float*)Outv;
    #pragma unroll
    for (int m = 0; m < 2; ++m) {
        #pragma unroll
        for (int n = 0; n < 2; ++n) {
            const int col = n0 + wc * 32 + n * 16 + q;
            const float bn = (MODE == 0) ? 0.f : bias[col];
            #pragma unroll
            for (int rg = 0; rg < 4; ++rg) {
                const int row = m0 + wr * 32 + m * 16 + g * 4 + rg;
                float v = acc[m][n][rg];
                if (MODE == 0)      O16[(size_t)row * H_ + col] = (u16)f2bf(v);
                else if (MODE == 1) O16[(size_t)row * H_ + col] = (u16)f2bf(relu_(v + bn));
                else                Of[(size_t)row * H_ + col] = alpha * (v + bn);
            }
        }
    }
}

// ---------------------------------------------------------------------------
extern "C" void kernel_launch(void* const* d_in, const int* in_sizes, int n_in,
                              void* d_out, int out_size, void* d_ws, size_t ws_size,
                              hipStream_t stream)
{
    (void)in_sizes; (void)n_in; (void)out_size; (void)ws_size;
    const float* Hj   = (const float*)d_in[0];
    const float* Hi   = (const float*)d_in[1];
    const float* mask = (const float*)d_in[2];
    const float* Wpj  = (const float*)d_in[3];
    const float* Wpi  = (const float*)d_in[4];
    const float* Ws1  = (const float*)d_in[5];
    const float* bs1  = (const float*)d_in[6];
    const float* Ws2  = (const float*)d_in[7];
    const float* bs2  = (const float*)d_in[8];
    const float* Wv1  = (const float*)d_in[9];
    const float* bv1  = (const float*)d_in[10];
    const float* Wv2  = (const float*)d_in[11];
    const float* bv2  = (const float*)d_in[12];
    const float* alphaPtr = (const float*)d_in[13];
    float* out = (float*)d_out;

    char* w = (char*)d_ws;
    float* Zj   = (float*)(w);                       // 196608 B
    float* Zi   = (float*)(w + 196608);              // 196608 B
    float* Plog = (float*)(w + 393216);              // 8388608 B (fp32 logits)
    u16*   Pb   = (u16*)  (w + 8782080 - 256);       // keep simple explicit offsets below
    // explicit offsets (all 256-aligned):
    size_t oPlog = 393216;
    size_t oPb   = oPlog + 8388608;    // 8781824
    size_t oHiT  = oPb + 4194304;      // 12976128
    size_t oWv1b = oHiT + 3145728;     // 16121856
    size_t oWv2b = oWv1b + 3538944;    // 19660800
    size_t oCTX  = oWv2b + 1179648;    // 20840448; end = 23986176 (~24 MB)
    Plog = (float*)(w + oPlog);
    Pb   = (u16*)(w + oPb);
    u16* HiT  = (u16*)(w + oHiT);
    u16* Wv1b = (u16*)(w + oWv1b);
    u16* Wv2b = (u16*)(w + oWv2b);
    u16* CTX  = (u16*)(w + oCTX);
    u16* MSG  = (u16*)(w + oPlog);     // overlay Plog+Pb (dead by then): 9437184 B
    u16* X1   = (u16*)(w + oHiT);      // overlay HiT (dead after gemm0): 3145728 B

    // prep: weight converts + Hi transpose (independent of proj/pair)
    cvt_kernel<<<(H_ * VI_ / 4 + 255) / 256, 256, 0, stream>>>(Wv1, Wv1b, H_ * VI_ / 4);
    cvt_kernel<<<(H_ * OH_ / 4 + 255) / 256, 256, 0, stream>>>(Wv2, Wv2b, H_ * OH_ / 4);
    transpose_hi_kernel<<<dim3(S_ / 32, H_ / 32, B_), 256, 0, stream>>>(Hi, HiT);

    proj_kernel<<<B_ * S_, 256, 0, stream>>>(Hj, Hi, Wpj, Wpi, Zj, Zi);
    pair_mfma_kernel<<<dim3(S_ / 16, S_ / 64, B_), 256, 0, stream>>>(
        Zj, Zi, Ws1, Ws2, bs1, bs2, Plog);
    softmax_kernel<<<B_ * S_, 256, 0, stream>>>(mask, Plog, Pb);

    // ctx = probs @ H_i  -> CTX bf16
    mfma_gemm_kernel<0, S_><<<dim3(2048 / 64, H_ / 64), 256, 0, stream>>>(
        Pb, HiT, nullptr, nullptr, CTX);
    // msg_in = [ctx, Hj, ctx*Hj] bf16
    msgin_kernel<<<(2048 * 96) / 256, 256, 0, stream>>>(CTX, Hj, MSG);
    // X1 = relu(msg_in @ Wv1^T + b)
    mfma_gemm_kernel<1, VI_><<<dim3(2048 / 64, OH_ / 64), 256, 0, stream>>>(
        MSG, Wv1b, bv1, nullptr, X1);
    // out = alpha*(X1 @ Wv2^T + b)
    mfma_gemm_kernel<2, OH_><<<dim3(2048 / 64, H_ / 64), 256, 0, stream>>>(
        X1, Wv2b, bv2, alphaPtr, out);
}

// Round 4
// 256.507 us; speedup vs baseline: 2.6349x; 1.0350x over previous
//
#include <hip/hip_runtime.h>
#include <hip/hip_bf16.h>
#include <math.h>

#define B_ 2
#define S_ 1024
#define H_ 768
#define D_ 24
#define HID_ 96
#define OH_ 768
#define VI_ 2304

typedef short bf16x8 __attribute__((ext_vector_type(8)));
typedef float f32x4 __attribute__((ext_vector_type(4)));
typedef unsigned short u16;

static __device__ __forceinline__ float relu_(float x) { return x > 0.f ? x : 0.f; }

static __device__ __forceinline__ short f2bf(float f) {
    __hip_bfloat16 h = __float2bfloat16(f);
    return *reinterpret_cast<short*>(&h);
}
static __device__ __forceinline__ float bf2f(short s) {
    unsigned u = ((unsigned)(u16)s) << 16;
    return __uint_as_float(u);
}

static __device__ __forceinline__ void gl_lds16(const void* g, void* l) {
    __builtin_amdgcn_global_load_lds(
        (const __attribute__((address_space(1))) unsigned int*)g,
        (__attribute__((address_space(3))) unsigned int*)l, 16, 0, 0);
}

#define NEGF (-3.402823466e38f)

// ---------------------------------------------------------------------------
// K1: per-token projections Zj, Zi  [B,S,D]
// ---------------------------------------------------------------------------
__global__ __launch_bounds__(256) void proj_kernel(
    const float* __restrict__ Hj, const float* __restrict__ Hi,
    const float* __restrict__ Wpj, const float* __restrict__ Wpi,
    float* __restrict__ Zj, float* __restrict__ Zi)
{
    __shared__ float rowj[H_], rowi[H_];
    const int t = blockIdx.x;           // 0..B*S-1
    const int tid = threadIdx.x;
    const float* hj = Hj + (size_t)t * H_;
    const float* hi = Hi + (size_t)t * H_;
    for (int x = tid; x < H_; x += 256) { rowj[x] = hj[x]; rowi[x] = hi[x]; }
    __syncthreads();

    const int g = tid & 7;              // 8 threads per output
    for (int o = tid >> 3; o < 2 * D_; o += 32) {
        const float* row;
        const float* w;
        if (o < D_) { row = rowj; w = Wpj + o * H_; }
        else        { row = rowi; w = Wpi + (o - D_) * H_; }
        float s = 0.f;
        #pragma unroll 8
        for (int c = 0; c < H_ / 8; ++c) s += row[g + 8 * c] * w[g + 8 * c];
        s += __shfl_down(s, 4, 8);
        s += __shfl_down(s, 2, 8);
        s += __shfl_down(s, 1, 8);
        if (g == 0) {
            if (o < D_) Zj[(size_t)t * D_ + o] = s;
            else        Zi[(size_t)t * D_ + (o - D_)] = s;
        }
    }
}

// ---------------------------------------------------------------------------
// K2: pair logits via MFMA, divergence-free.
// Feature K-order (padded): step0=[Zi(24)|0*8], step1=[Zj*Zi|0*8],
// step2=[|Zj-Zi||0*8]. Zj-linear + bias folded into per-(j,k) Aterm used as
// MFMA C-in. Operands swapped: mfma(W, F, acc) -> D row=k, col=pair, so the
// w2-dot reduce is 2 shfl_xor. Zi tiles XOR-swizzled in 16B granules.
// ---------------------------------------------------------------------------
__global__ __launch_bounds__(256) void pair_mfma_kernel(
    const float* __restrict__ Zj, const float* __restrict__ Zi,
    const float* __restrict__ Ws1, const float* __restrict__ Ws2,
    const float* __restrict__ bs1, const float* __restrict__ bs2,
    float* __restrict__ P)
{
    __shared__ float sZj32[16 * 32];    // plain, cols 24..31 = 0
    __shared__ float sZi32[64 * 32];    // granule(4f) at d^(row&7)
    __shared__ u16   sZi16[64 * 64];    // granule(8h) at c^(row&7), c<4
    __shared__ float sAterm[16 * 96];   // [j][k]
    __shared__ float sW1a[96 * 25];
    __shared__ float sW2[96];

    const int j0 = blockIdx.x * 16, i0 = blockIdx.y * 64, b = blockIdx.z;
    const int tid = threadIdx.x;
    const int lane = tid & 63, wv = tid >> 6;
    const int q = lane & 15, g = lane >> 4;

    // ---- stage tiles ----
    if (tid < 128) {                    // zj32: 16 rows x 8 granules
        int r = tid >> 3, d = tid & 7;
        float4 v = make_float4(0.f, 0.f, 0.f, 0.f);
        if (d < 6) v = *(const float4*)&Zj[((size_t)(b * S_ + j0 + r)) * D_ + 4 * d];
        *(float4*)&sZj32[r * 32 + 4 * d] = v;
    }
    for (int t = tid; t < 512; t += 256) {   // zi32: 64 rows x 8 granules
        int r = t >> 3, d = t & 7;
        int gr = d ^ (r & 7);
        float4 v = make_float4(0.f, 0.f, 0.f, 0.f);
        if (d < 6) v = *(const float4*)&Zi[((size_t)(b * S_ + i0 + r)) * D_ + 4 * d];
        *(float4*)&sZi32[r * 32 + 4 * gr] = v;
    }
    {                                   // zi16: 64 rows x 4 granules (8 shorts)
        int r = tid >> 2, c = tid & 3;
        int gr = c ^ (r & 7);
        bf16x8 o = {0, 0, 0, 0, 0, 0, 0, 0};
        if (c < 3) {
            const float* src = &Zi[((size_t)(b * S_ + i0 + r)) * D_ + 8 * c];
            #pragma unroll
            for (int e = 0; e < 8; ++e) o[e] = f2bf(src[e]);
        }
        *(bf16x8*)&sZi16[r * 64 + 8 * gr] = o;
    }
    for (int t = tid; t < 96 * 24; t += 256) {
        int k = t / 24, d = t - k * 24;
        sW1a[k * 25 + d] = Ws1[(size_t)k * 96 + d];
    }
    if (tid < 96) sW2[tid] = Ws2[tid];
    __syncthreads();

    // ---- Aterm[j][k] = bs1[k] + W1a[k,:] . zj[j,:]  (fp32) ----
    for (int o = tid; o < 16 * 96; o += 256) {
        int j = o / 96, k = o - j * 96;
        float acc = bs1[k];
        #pragma unroll
        for (int d = 0; d < 24; ++d) acc += sW1a[k * 25 + d] * sZj32[j * 32 + d];
        sAterm[o] = acc;
    }

    // ---- weight fragments (A-operand): wf[s][nt], lane holds
    // Ws1[nt*16+q][24*(s+1) + 8g .. +7], zeros for g==3 (K-padding) ----
    bf16x8 wf[3][6];
    #pragma unroll
    for (int s = 0; s < 3; ++s)
        #pragma unroll
        for (int nt = 0; nt < 6; ++nt) {
            bf16x8 t8 = {0, 0, 0, 0, 0, 0, 0, 0};
            if (g < 3) {
                const float* wp = Ws1 + (size_t)(nt * 16 + q) * 96 + 24 * (s + 1) + 8 * g;
                #pragma unroll
                for (int e = 0; e < 8; ++e) t8[e] = f2bf(wp[e]);
            }
            wf[s][nt] = t8;
        }
    const float b2 = bs2[0];
    __syncthreads();

    // ---- main loop: wave wv owns jj = wv*4+jq; 4 i-subtiles of 16 ----
    for (int jq = 0; jq < 4; ++jq) {
        const int jj = wv * 4 + jq;
        const f32x4 zjA = *(const f32x4*)&sZj32[jj * 32 + 8 * g];
        const f32x4 zjB = *(const f32x4*)&sZj32[jj * 32 + 8 * g + 4];
        f32x4 At[6];
        #pragma unroll
        for (int nt = 0; nt < 6; ++nt)
            At[nt] = *(const f32x4*)&sAterm[jj * 96 + nt * 16 + 4 * g];

        #pragma unroll
        for (int ib = 0; ib < 4; ++ib) {
            const int ii = ib * 16 + q;
            const int sw = ii & 7;
            bf16x8 af1 = *(const bf16x8*)&sZi16[ii * 64 + 8 * (g ^ sw)];
            f32x4 zi0 = *(const f32x4*)&sZi32[ii * 32 + 4 * ((2 * g) ^ sw)];
            f32x4 zi1 = *(const f32x4*)&sZi32[ii * 32 + 4 * ((2 * g + 1) ^ sw)];
            bf16x8 af2, af3;
            #pragma unroll
            for (int e = 0; e < 4; ++e) {
                af2[e]     = f2bf(zjA[e] * zi0[e]);
                af2[e + 4] = f2bf(zjB[e] * zi1[e]);
                af3[e]     = f2bf(fabsf(zjA[e] - zi0[e]));
                af3[e + 4] = f2bf(fabsf(zjB[e] - zi1[e]));
            }
            f32x4 acc[6];
            #pragma unroll
            for (int nt = 0; nt < 6; ++nt) acc[nt] = At[nt];
            #pragma unroll
            for (int nt = 0; nt < 6; ++nt) {
                acc[nt] = __builtin_amdgcn_mfma_f32_16x16x32_bf16(wf[0][nt], af1, acc[nt], 0, 0, 0);
                acc[nt] = __builtin_amdgcn_mfma_f32_16x16x32_bf16(wf[1][nt], af2, acc[nt], 0, 0, 0);
                acc[nt] = __builtin_amdgcn_mfma_f32_16x16x32_bf16(wf[2][nt], af3, acc[nt], 0, 0, 0);
            }
            float lg = 0.f;
            #pragma unroll
            for (int nt = 0; nt < 6; ++nt) {
                f32x4 w2v = *(const f32x4*)&sW2[nt * 16 + 4 * g];
                #pragma unroll
                for (int r = 0; r < 4; ++r) lg += w2v[r] * relu_(acc[nt][r]);
            }
            lg += __shfl_xor(lg, 16);
            lg += __shfl_xor(lg, 32);
            if (lane < 16)
                P[((size_t)(b * S_ + j0 + jj)) * S_ + i0 + ib * 16 + lane] = lg + b2;
        }
    }
}

// ---------------------------------------------------------------------------
// K3: row softmax over i (additive key mask); reads fp32 logits, writes bf16
// ---------------------------------------------------------------------------
__global__ __launch_bounds__(256) void softmax_kernel(
    const float* __restrict__ mask, const float* __restrict__ P,
    u16* __restrict__ Pb)
{
    const int r = blockIdx.x;           // b*S + j
    const int b = r / S_;
    const int tid = threadIdx.x;
    const float* row = P + (size_t)r * S_;
    __shared__ float red[4];

    float v[4];
    float mx = -INFINITY;
    #pragma unroll
    for (int c = 0; c < 4; ++c) {
        int i = tid + 256 * c;
        float m = mask[b * S_ + i];
        v[c] = row[i] + (1.0f - m) * NEGF;
        mx = fmaxf(mx, v[c]);
    }
    for (int off = 32; off > 0; off >>= 1) mx = fmaxf(mx, __shfl_xor(mx, off));
    if ((tid & 63) == 0) red[tid >> 6] = mx;
    __syncthreads();
    mx = fmaxf(fmaxf(red[0], red[1]), fmaxf(red[2], red[3]));

    float s = 0.f;
    #pragma unroll
    for (int c = 0; c < 4; ++c) { v[c] = __expf(v[c] - mx); s += v[c]; }
    for (int off = 32; off > 0; off >>= 1) s += __shfl_xor(s, off);
    __syncthreads();
    if ((tid & 63) == 0) red[tid >> 6] = s;
    __syncthreads();
    s = red[0] + red[1] + red[2] + red[3];
    const float inv = 1.0f / s;
    #pragma unroll
    for (int c = 0; c < 4; ++c)
        Pb[(size_t)r * S_ + tid + 256 * c] = (u16)f2bf(v[c] * inv);
}

// ---------------------------------------------------------------------------
// Prep kernels: fp32->bf16 convert, Hi transpose, msg_in build
// ---------------------------------------------------------------------------
__global__ __launch_bounds__(256) void cvt_kernel(
    const float* __restrict__ src, u16* __restrict__ dst, int n4)
{
    int i = blockIdx.x * 256 + threadIdx.x;
    if (i >= n4) return;
    float4 v = ((const float4*)src)[i];
    ushort4 o;
    o.x = (u16)f2bf(v.x); o.y = (u16)f2bf(v.y);
    o.z = (u16)f2bf(v.z); o.w = (u16)f2bf(v.w);
    ((ushort4*)dst)[i] = o;
}

__global__ __launch_bounds__(256) void transpose_hi_kernel(
    const float* __restrict__ Hi, u16* __restrict__ HiT)
{
    __shared__ u16 t[32][33];
    const int i0 = blockIdx.x * 32, h0 = blockIdx.y * 32, b = blockIdx.z;
    const int c = threadIdx.x & 31, r = threadIdx.x >> 5;   // r: 0..7
    #pragma unroll
    for (int rr = r; rr < 32; rr += 8)
        t[rr][c] = (u16)f2bf(Hi[((size_t)(b * S_ + i0 + rr)) * H_ + h0 + c]);
    __syncthreads();
    #pragma unroll
    for (int rr = r; rr < 32; rr += 8)
        HiT[((size_t)(b * H_ + h0 + rr)) * S_ + i0 + c] = t[c][rr];
}

__global__ __launch_bounds__(256) void msgin_kernel(
    const u16* __restrict__ ctx, const float* __restrict__ Hj,
    u16* __restrict__ MSG)
{
    const int idx = blockIdx.x * 256 + threadIdx.x;   // < 2048*96
    const int m = idx / 96, c8 = (idx % 96) * 8;
    bf16x8 c = *(const bf16x8*)&ctx[(size_t)m * H_ + c8];
    float4 h0 = *(const float4*)&Hj[(size_t)m * H_ + c8];
    float4 h1 = *(const float4*)&Hj[(size_t)m * H_ + c8 + 4];
    float hf[8] = {h0.x, h0.y, h0.z, h0.w, h1.x, h1.y, h1.z, h1.w};
    bf16x8 hb, pb;
    #pragma unroll
    for (int e = 0; e < 8; ++e) {
        hb[e] = f2bf(hf[e]);
        pb[e] = f2bf(bf2f(c[e]) * hf[e]);
    }
    u16* row = MSG + (size_t)m * VI_;
    *(bf16x8*)&row[c8]        = c;
    *(bf16x8*)&row[768 + c8]  = hb;
    *(bf16x8*)&row[1536 + c8] = pb;
}

// ---------------------------------------------------------------------------
// bf16 MFMA GEMM: C[2048,768] = A[2048,K] x B[768,K]^T
// 64x64 tile, BK=64, 4 waves (2x2, 32x32 each), dbuf LDS, global_load_lds(16),
// chunk-XOR swizzle (c ^= row&7) pre-applied on global source, applied on read.
// ---------------------------------------------------------------------------
template<int MODE, int K>
__global__ __launch_bounds__(256) void mfma_gemm_kernel(
    const u16* __restrict__ Ag, const u16* __restrict__ Bg,
    const float* __restrict__ bias, const float* __restrict__ alphaPtr,
    void* __restrict__ Outv)
{
    __shared__ u16 As[2][64 * 64];
    __shared__ u16 Bs[2][64 * 64];
    const int tid = threadIdx.x;
    const int lane = tid & 63, wv = tid >> 6;
    const int q = lane & 15, g = lane >> 4;
    const int wr = wv >> 1, wc = wv & 1;
    const int m0 = blockIdx.x * 64, n0 = blockIdx.y * 64;

    const u16* Ab = Ag + (size_t)m0 * K;
    const u16* Bb = (MODE == 0)
        ? Bg + (size_t)(m0 >> 10) * H_ * S_ + (size_t)n0 * K
        : Bg + (size_t)n0 * K;

    int st_r[2], st_gc[2], st_dst[2];
    #pragma unroll
    for (int it = 0; it < 2; ++it) {
        int cidx = (it * 4 + wv) * 64 + lane;
        st_r[it] = cidx >> 3;
        st_gc[it] = (cidx & 7) ^ (st_r[it] & 7);
        st_dst[it] = cidx * 8;
    }

    f32x4 acc[2][2] = {};

    auto stage = [&](int buf, int k0) {
        #pragma unroll
        for (int it = 0; it < 2; ++it) {
            gl_lds16(Ab + (size_t)st_r[it] * K + k0 + st_gc[it] * 8,
                     &As[buf][st_dst[it]]);
            gl_lds16(Bb + (size_t)st_r[it] * K + k0 + st_gc[it] * 8,
                     &Bs[buf][st_dst[it]]);
        }
    };
    auto comp = [&](int buf) {
        #pragma unroll
        for (int ks = 0; ks < 2; ++ks) {
            bf16x8 af[2], bfr[2];
            #pragma unroll
            for (int m = 0; m < 2; ++m) {
                int r = wr * 32 + m * 16 + q;
                int cl = (g + ks * 4) ^ (r & 7);
                af[m] = *(const bf16x8*)&As[buf][r * 64 + cl * 8];
            }
            #pragma unroll
            for (int n = 0; n < 2; ++n) {
                int r = wc * 32 + n * 16 + q;
                int cl = (g + ks * 4) ^ (r & 7);
                bfr[n] = *(const bf16x8*)&Bs[buf][r * 64 + cl * 8];
            }
            #pragma unroll
            for (int m = 0; m < 2; ++m)
                #pragma unroll
                for (int n = 0; n < 2; ++n)
                    acc[m][n] = __builtin_amdgcn_mfma_f32_16x16x32_bf16(
                        af[m], bfr[n], acc[m][n], 0, 0, 0);
        }
    };

    constexpr int NT = K / 64;
    stage(0, 0);
    __syncthreads();
    int cur = 0;
    for (int kt = 0; kt < NT - 1; ++kt) {
        stage(cur ^ 1, (kt + 1) * 64);
        comp(cur);
        __syncthreads();
        cur ^= 1;
    }
    comp(cur);

    const float alpha = (MODE == 2) ? alphaPtr[0] : 0.f;
    u16* O16 = (u16*)Outv;
    float* Of = (float*)Outv;
    #pragma unroll
    for (int m = 0; m < 2; ++m) {
        #pragma unroll
        for (int n = 0; n < 2; ++n) {
            const int col = n0 + wc * 32 + n * 16 + q;
            const float bn = (MODE == 0) ? 0.f : bias[col];
            #pragma unroll
            for (int rg = 0; rg < 4; ++rg) {
                const int row = m0 + wr * 32 + m * 16 + g * 4 + rg;
                float v = acc[m][n][rg];
                if (MODE == 0)      O16[(size_t)row * H_ + col] = (u16)f2bf(v);
                else if (MODE == 1) O16[(size_t)row * H_ + col] = (u16)f2bf(relu_(v + bn));
                else                Of[(size_t)row * H_ + col] = alpha * (v + bn);
            }
        }
    }
}

// ---------------------------------------------------------------------------
extern "C" void kernel_launch(void* const* d_in, const int* in_sizes, int n_in,
                              void* d_out, int out_size, void* d_ws, size_t ws_size,
                              hipStream_t stream)
{
    (void)in_sizes; (void)n_in; (void)out_size; (void)ws_size;
    const float* Hj   = (const float*)d_in[0];
    const float* Hi   = (const float*)d_in[1];
    const float* mask = (const float*)d_in[2];
    const float* Wpj  = (const float*)d_in[3];
    const float* Wpi  = (const float*)d_in[4];
    const float* Ws1  = (const float*)d_in[5];
    const float* bs1  = (const float*)d_in[6];
    const float* Ws2  = (const float*)d_in[7];
    const float* bs2  = (const float*)d_in[8];
    const float* Wv1  = (const float*)d_in[9];
    const float* bv1  = (const float*)d_in[10];
    const float* Wv2  = (const float*)d_in[11];
    const float* bv2  = (const float*)d_in[12];
    const float* alphaPtr = (const float*)d_in[13];
    float* out = (float*)d_out;

    char* w = (char*)d_ws;
    float* Zj   = (float*)(w);                       // 196608 B
    float* Zi   = (float*)(w + 196608);              // 196608 B
    size_t oPlog = 393216;
    size_t oPb   = oPlog + 8388608;    // 8781824
    size_t oHiT  = oPb + 4194304;      // 12976128
    size_t oWv1b = oHiT + 3145728;     // 16121856
    size_t oWv2b = oWv1b + 3538944;    // 19660800
    size_t oCTX  = oWv2b + 1179648;    // 20840448; end ~24 MB
    float* Plog = (float*)(w + oPlog);
    u16* Pb   = (u16*)(w + oPb);
    u16* HiT  = (u16*)(w + oHiT);
    u16* Wv1b = (u16*)(w + oWv1b);
    u16* Wv2b = (u16*)(w + oWv2b);
    u16* CTX  = (u16*)(w + oCTX);
    u16* MSG  = (u16*)(w + oPlog);     // overlay Plog+Pb (dead by then)
    u16* X1   = (u16*)(w + oHiT);      // overlay HiT (dead after gemm0)

    cvt_kernel<<<(H_ * VI_ / 4 + 255) / 256, 256, 0, stream>>>(Wv1, Wv1b, H_ * VI_ / 4);
    cvt_kernel<<<(H_ * OH_ / 4 + 255) / 256, 256, 0, stream>>>(Wv2, Wv2b, H_ * OH_ / 4);
    transpose_hi_kernel<<<dim3(S_ / 32, H_ / 32, B_), 256, 0, stream>>>(Hi, HiT);

    proj_kernel<<<B_ * S_, 256, 0, stream>>>(Hj, Hi, Wpj, Wpi, Zj, Zi);
    pair_mfma_kernel<<<dim3(S_ / 16, S_ / 64, B_), 256, 0, stream>>>(
        Zj, Zi, Ws1, Ws2, bs1, bs2, Plog);
    softmax_kernel<<<B_ * S_, 256, 0, stream>>>(mask, Plog, Pb);

    mfma_gemm_kernel<0, S_><<<dim3(2048 / 64, H_ / 64), 256, 0, stream>>>(
        Pb, HiT, nullptr, nullptr, CTX);
    msgin_kernel<<<(2048 * 96) / 256, 256, 0, stream>>>(CTX, Hj, MSG);
    mfma_gemm_kernel<1, VI_><<<dim3(2048 / 64, OH_ / 64), 256, 0, stream>>>(
        MSG, Wv1b, bv1, nullptr, X1);
    mfma_gemm_kernel<2, OH_><<<dim3(2048 / 64, H_ / 64), 256, 0, stream>>>(
        X1, Wv2b, bv2, alphaPtr, out);
}